// Round 16
// baseline (270.635 us; speedup 1.0000x reference)
//
#include <hip/hip_runtime.h>

// NCC loss: 1 - mean( cross^2 / (pvar*tvar + 1e-8) ) over 9^3 zero-padded
// box windows, input (4,1,160,160,160) fp32.
//
// R21: R20's XCD swizzle made the problem cache-resident (FETCH 331->72MB,
// HBM 6.6% of peak) and scored best (bench 214.1us). That unlocks R11's
// ringless design, which failed ONLY because its z-9 re-read missed cache
// and became HBM-BW-bound (627MB @ 3.2TB/s). R21 = R16+swizzle structure
// with the 54-float register ring DELETED:
//   - subtract slice z-9 RE-READ from global (local-L2/L3 hit under the
//     swizzle; HBM has 15x headroom);
//   - BOTH add- and sub-slice prefetched a FULL STEP ahead (R11 consumed
//     the sub-read ~20 insts after issue; here L2 latency << step time);
//   - gate zS >= zlo (= max(z0-4,0)) reproduces the ring's zero slots
//     (R11-verified, absmax 0);
//   - register state ~55 (zs 15 + 2x prefetch 12 + temps), no AGPR ring ->
//     launch_bounds(256,6): 6 blocks/CU, 24 waves/CU, and per-step staging
//     loses the 30 ring ops; warm-up halves (no ring stores).
// Everything else R16/R20-verbatim: 3 cols/thread all-lane staging, DPP
// shl1-3 x-prefix, 3 stg + 1 red wave, ZCHUNK 40, one barrier/step,
// double-buffered s2, bijective XCD swizzle (1600%8==0).
// Tripwires: WRITE_SIZE ~50KB (spill -> retry at (256,5)); FETCH must stay
// <~150MB (if ~600MB the L2-local assumption failed -> reject).

#define DSZ    160
#define NBATCH 4
#define RAD    4
#define TX     16
#define TY     16
#define ZCHUNK 40
#define SLICE  (DSZ*DSZ)
#define VOL    (DSZ*DSZ*DSZ)
#define WINV   (1.0f/729.0f)
#define NVOX_INV (1.0f/16384000.0f)

#define NROW 24        // halo rows per tile
#define BLK  256       // 3 staging waves (tid<192, all active) + 1 reduction wave

#define S2_RS 20                 // row stride: 16 outputs + pad
#define S2_FS (NROW*S2_RS)       // 480 floats per field
#define S2_BUF (5*S2_FS)         // 2400 floats per parity buffer

__device__ __forceinline__ float dpp_shl1(float x) {  // lane i <- lane i+1 (16-lane row, OOB=0)
    return __int_as_float(__builtin_amdgcn_update_dpp(0, __float_as_int(x), 0x101, 0xf, 0xf, true));
}
__device__ __forceinline__ float dpp_shl2(float x) {  // lane i <- lane i+2
    return __int_as_float(__builtin_amdgcn_update_dpp(0, __float_as_int(x), 0x102, 0xf, 0xf, true));
}
__device__ __forceinline__ float dpp_shl3(float x) {  // lane i <- lane i+3
    return __int_as_float(__builtin_amdgcn_update_dpp(0, __float_as_int(x), 0x103, 0xf, 0xf, true));
}

__global__ __launch_bounds__(BLK, 6)
void ncc_main(const float* __restrict__ pred, const float* __restrict__ tgt,
              float* __restrict__ accum)
{
    const int tid = threadIdx.x;
    const int row = tid >> 3;      // 0..23 halo row (staging threads)
    const int g   = tid & 7;       // 0..7 col-triple group; ALL active

    // ---- XCD-aware bijective swizzle (T1): hw bid -> logical tile ----
    const int bid = blockIdx.x + 10*(blockIdx.y + 10*blockIdx.z);
    const int lid = (bid & 7)*200 + (bid >> 3);       // bijective: 1600%8==0
    const int lz  = lid / 100;                        // 0..15: (batch,chunk)
    const int lxy = lid - lz*100;
    const int ly  = lxy / 10;
    const int lx  = lxy - ly*10;

    const int ox  = lx * TX;
    const int oy  = ly * TY;
    const int batch = lz >> 2;
    const int z0  = (lz & 3) * ZCHUNK;

    __shared__ float s2[2*S2_BUF];   // 19.2 KB, double-buffered [f][y][x pad20]

    const bool stg = (tid < 192);
    const bool red = (tid >= 192);               // dedicated reduction wave
    const int  gy  = oy - RAD + row;
    const int  gx0 = ox - RAD + g*3;             // 3 halo cols per thread
    const bool ldok = stg && (gy >= 0) && (gy < DSZ) && (gx0 >= 0) && (gx0 + 2 < DSZ);
    const int  base = batch*VOL + gy*DSZ + gx0;  // only used under ldok

    // running z-window sums (5 fields x own 3 columns); NO ring
    float zs[5][3];
    #pragma unroll
    for (int f = 0; f < 5; ++f)
        #pragma unroll
        for (int j = 0; j < 3; ++j) zs[f][j] = 0.f;

    const int zlo = (z0 - RAD < 0) ? 0 : (z0 - RAD);   // lowest z accumulated

    // ---- warm-up: slices z0-4 .. z0+3 into zs ----
    if (stg) {
        #pragma unroll
        for (int i = 0; i < 8; ++i) {
            int z = z0 - RAD + i;
            if (z >= 0) {                       // uniform; z < DSZ always here
                float3 p3 = {0,0,0}, t3 = {0,0,0};
                if (ldok) {
                    p3 = *(const float3*)(pred + base + z*SLICE);
                    t3 = *(const float3*)(tgt  + base + z*SLICE);
                }
                const float pc[3] = {p3.x, p3.y, p3.z};
                const float tc[3] = {t3.x, t3.y, t3.z};
                #pragma unroll
                for (int j = 0; j < 3; ++j) {
                    zs[0][j] += pc[j];        zs[1][j] += tc[j];
                    zs[2][j] += pc[j]*pc[j];  zs[3][j] += tc[j]*tc[j];
                    zs[4][j] += pc[j]*tc[j];
                }
            }
        }
    }

    // ---- depth-1 prefetch of BOTH next add-slice (za) and sub-slice (za-9)
    int za = z0 + RAD;                      // absolute z of next add fetch
    int zmax = z0 + ZCHUNK + RAD;           // last useful slice + 1
    if (zmax > DSZ) zmax = DSZ;
    float3 pa3 = {0,0,0}, ta3 = {0,0,0};    // add slice
    float3 ps3 = {0,0,0}, ts3 = {0,0,0};    // sub slice (z-9)

#define PF_NEXT() do {                                                        \
    float3 _pa = {0,0,0}, _ta = {0,0,0}, _ps = {0,0,0}, _ts = {0,0,0};        \
    if (ldok) {                                                               \
        if (za < zmax) {                                                      \
            _pa = *(const float3*)(pred + base + za*SLICE);                   \
            _ta = *(const float3*)(tgt  + base + za*SLICE);                   \
        }                                                                     \
        if (za - 9 >= zlo) {                                                  \
            _ps = *(const float3*)(pred + base + (za-9)*SLICE);               \
            _ts = *(const float3*)(tgt  + base + (za-9)*SLICE);               \
        }                                                                     \
    }                                                                         \
    pa3 = _pa; ta3 = _ta; ps3 = _ps; ts3 = _ts; ++za;                         \
} while (0)

    if (stg) PF_NEXT();  // pair for step 0

    float acc = 0.f;

#define NCC_STEP(BUFI) do {                                                   \
    float* s2w = s2 + (BUFI)*S2_BUF;                                          \
    if (stg) {                                                                \
        const float pc[3]  = {pa3.x, pa3.y, pa3.z};                           \
        const float tc[3]  = {ta3.x, ta3.y, ta3.z};                           \
        const float psv[3] = {ps3.x, ps3.y, ps3.z};                           \
        const float tsv[3] = {ts3.x, ts3.y, ts3.z};                           \
        PF_NEXT();  /* issue step s+1's add+sub; full step to complete */     \
        _Pragma("unroll")                                                     \
        for (int j = 0; j < 3; ++j) {                                         \
            float ps = psv[j], qs = tsv[j];                                   \
            float d0 = pc[j] - ps, d1 = tc[j] - qs;                           \
            zs[0][j] += d0;                                                   \
            zs[1][j] += d1;                                                   \
            zs[2][j] += d0*(pc[j] + ps);                                      \
            zs[3][j] += d1*(tc[j] + qs);                                      \
            zs[4][j] += pc[j]*tc[j] - ps*qs;                                  \
        }                                                                     \
        _Pragma("unroll")                                                     \
        for (int f = 0; f < 5; ++f) {                                         \
            float v0  = zs[f][0];                                             \
            float v01 = v0 + zs[f][1];                                        \
            float G   = v01 + zs[f][2];        /* 3-col group sum */          \
            float G1 = dpp_shl1(G);                                           \
            float G2 = dpp_shl2(G);                                           \
            float A0 = dpp_shl3(v0);           /* v0(m+3)  */                 \
            float A1 = dpp_shl3(v01);          /* v01(m+3) */                 \
            float S  = G + G1 + G2;            /* halo cols 3m..3m+8 */       \
            float* dst = &s2w[f*S2_FS + row*S2_RS + 3*g];                     \
            if (g < 5) {                                                      \
                dst[0] = S;                    /* out 3m   */                 \
                dst[1] = S - v0  + A0;         /* out 3m+1 */                 \
                dst[2] = S - v01 + A1;         /* out 3m+2 */                 \
            } else if (g == 5) {                                              \
                dst[0] = S;                    /* out 15   */                 \
            }                                                                 \
        }                                                                     \
    }                                                                         \
    __syncthreads();                                                          \
    if (red) {                                                                \
        const int x = tid & 15, yq = ((tid >> 4) & 3)*4;                      \
        float S[5][4];                                                        \
        _Pragma("unroll")                                                     \
        for (int f = 0; f < 5; ++f) {                                         \
            const float* col = &s2w[f*S2_FS + x];                             \
            float r0 = col[(yq+0)*S2_RS], r1 = col[(yq+1)*S2_RS];             \
            float r2 = col[(yq+2)*S2_RS], r3 = col[(yq+3)*S2_RS];             \
            float run = r0+r1+r2+r3 + col[(yq+4)*S2_RS] + col[(yq+5)*S2_RS]   \
                      + col[(yq+6)*S2_RS] + col[(yq+7)*S2_RS];                \
            run += col[(yq+8)*S2_RS];        S[f][0] = run;                   \
            run += col[(yq+9)*S2_RS]  - r0;  S[f][1] = run;                   \
            run += col[(yq+10)*S2_RS] - r1;  S[f][2] = run;                   \
            run += col[(yq+11)*S2_RS] - r2;  S[f][3] = run;                   \
        }                                                                     \
        _Pragma("unroll")                                                     \
        for (int i = 0; i < 4; ++i) {                                         \
            float Sp = S[0][i], St = S[1][i];                                 \
            float cross = S[4][i] - Sp*St*WINV;                               \
            float pv    = S[2][i] - Sp*Sp*WINV;                               \
            float tv    = S[3][i] - St*St*WINV;                               \
            acc += cross*cross / (pv*tv + 1e-8f);                             \
        }                                                                     \
    }                                                                         \
} while (0)

    // 40 steps, static buffer parity (2 steps per iteration)
    for (int it = 0; it < ZCHUNK/2; ++it) {
        NCC_STEP(0);
        NCC_STEP(1);
    }
#undef NCC_STEP
#undef PF_NEXT

    // all cc partials live in the reduction wave (tid 192..255)
    if (red) {
        float v = acc;
        #pragma unroll
        for (int off = 32; off > 0; off >>= 1) v += __shfl_down(v, off, 64);
        if (tid == 192) atomicAdd(accum, v);
    }
}

__global__ void ncc_final(const float* __restrict__ accum, float* __restrict__ out)
{
    out[0] = 1.0f - accum[0] * NVOX_INV;
}

extern "C" void kernel_launch(void* const* d_in, const int* in_sizes, int n_in,
                              void* d_out, int out_size, void* d_ws, size_t ws_size,
                              hipStream_t stream)
{
    const float* pred = (const float*)d_in[0];
    const float* tgt  = (const float*)d_in[1];
    float* out = (float*)d_out;
    float* ws  = (float*)d_ws;

    hipMemsetAsync(ws, 0, sizeof(float), stream);
    dim3 grid(DSZ/TX, DSZ/TY, NBATCH*4);   // 10 x 10 x 16 = 1600 blocks
    ncc_main<<<grid, BLK, 0, stream>>>(pred, tgt, ws);
    ncc_final<<<1, 1, 0, stream>>>(ws, out);
}

// Round 17
// 256.023 us; speedup vs baseline: 1.0571x; 1.0571x over previous
//
#include <hip/hip_runtime.h>

// NCC loss: 1 - mean( cross^2 / (pvar*tvar + 1e-8) ) over 9^3 zero-padded
// box windows, input (4,1,160,160,160) fp32.
//
// R22: R21 (ringless + L2 re-read) lost 26% despite its premise holding
// (FETCH 132MB, occ 43%) — the 2 extra loads/step on the issue path + 4-load
// vmcnt drain beat the 30 saved ring-VALU ops. Reverted to R20 (bench 214us,
// best): R16 + bijective XCD swizzle. All structural levers now tested both
// directions; last untested cost is launch structure. R22 = R20 + FUSED
// EPILOGUE: ncc_final's work moves into ncc_main via a device-scope
// completion counter (accum add -> threadfence -> counter add; the 1600th
// incrementer re-reads accum with an atomic RMW — cross-XCD coherent — and
// writes out[0]). One dispatch instead of two. Kernel body R20-verbatim.
// ws layout: ws[0]=accum (float), ws[1]=counter (uint); memset zeroes 8B.

#define DSZ    160
#define NBATCH 4
#define RAD    4
#define TX     16
#define TY     16
#define ZCHUNK 40
#define SLICE  (DSZ*DSZ)
#define VOL    (DSZ*DSZ*DSZ)
#define WINV   (1.0f/729.0f)
#define NVOX_INV (1.0f/16384000.0f)

#define NROW 24        // halo rows per tile
#define BLK  256       // 3 staging waves (tid<192, all active) + 1 reduction wave
#define NBLOCKS 1600

#define S2_RS 20                 // row stride: 16 outputs + pad
#define S2_FS (NROW*S2_RS)       // 480 floats per field
#define S2_BUF (5*S2_FS)         // 2400 floats per parity buffer

__device__ __forceinline__ float dpp_shl1(float x) {  // lane i <- lane i+1 (16-lane row, OOB=0)
    return __int_as_float(__builtin_amdgcn_update_dpp(0, __float_as_int(x), 0x101, 0xf, 0xf, true));
}
__device__ __forceinline__ float dpp_shl2(float x) {  // lane i <- lane i+2
    return __int_as_float(__builtin_amdgcn_update_dpp(0, __float_as_int(x), 0x102, 0xf, 0xf, true));
}
__device__ __forceinline__ float dpp_shl3(float x) {  // lane i <- lane i+3
    return __int_as_float(__builtin_amdgcn_update_dpp(0, __float_as_int(x), 0x103, 0xf, 0xf, true));
}

__global__ __launch_bounds__(BLK, 4)
void ncc_main(const float* __restrict__ pred, const float* __restrict__ tgt,
              float* __restrict__ accum, unsigned int* __restrict__ counter,
              float* __restrict__ out)
{
    const int tid = threadIdx.x;
    const int row = tid >> 3;      // 0..23 halo row (staging threads)
    const int g   = tid & 7;       // 0..7 col-triple group; ALL active

    // ---- XCD-aware bijective swizzle (T1): hw bid -> logical tile ----
    const int bid = blockIdx.x + 10*(blockIdx.y + 10*blockIdx.z);
    const int lid = (bid & 7)*200 + (bid >> 3);       // bijective: 1600%8==0
    const int lz  = lid / 100;                        // 0..15: (batch,chunk)
    const int lxy = lid - lz*100;
    const int ly  = lxy / 10;
    const int lx  = lxy - ly*10;

    const int ox  = lx * TX;
    const int oy  = ly * TY;
    const int batch = lz >> 2;
    const int z0  = (lz & 3) * ZCHUNK;

    __shared__ float s2[2*S2_BUF];   // 19.2 KB, double-buffered [f][y][x pad20]

    const bool stg = (tid < 192);
    const bool red = (tid >= 192);               // dedicated reduction wave
    const int  gy  = oy - RAD + row;
    const int  gx0 = ox - RAD + g*3;             // 3 halo cols per thread
    const bool ldok = stg && (gy >= 0) && (gy < DSZ) && (gx0 >= 0) && (gx0 + 2 < DSZ);
    const int  base = batch*VOL + gy*DSZ + gx0;  // only used under ldok

    // register ring of raw slice values (own 3 columns), chunk-local slots
    float rp[9][3], rt[9][3];
    float zs[5][3];
    #pragma unroll
    for (int k = 0; k < 9; ++k)
        #pragma unroll
        for (int j = 0; j < 3; ++j) { rp[k][j] = 0.f; rt[k][j] = 0.f; }
    #pragma unroll
    for (int f = 0; f < 5; ++f)
        #pragma unroll
        for (int j = 0; j < 3; ++j) zs[f][j] = 0.f;

    // ---- warm-up: chunk-local slices 0..7 (z = z0-4 .. z0+3) -> slots 0..7
    if (stg) {
        #pragma unroll
        for (int i = 0; i < 8; ++i) {
            int z = z0 - RAD + i;
            if (z >= 0) {                       // uniform; z < DSZ always here
                float3 p3 = {0,0,0}, t3 = {0,0,0};
                if (ldok) {
                    p3 = *(const float3*)(pred + base + z*SLICE);
                    t3 = *(const float3*)(tgt  + base + z*SLICE);
                }
                const float pc[3] = {p3.x, p3.y, p3.z};
                const float tc[3] = {t3.x, t3.y, t3.z};
                #pragma unroll
                for (int j = 0; j < 3; ++j) {
                    zs[0][j] += pc[j];        zs[1][j] += tc[j];
                    zs[2][j] += pc[j]*pc[j];  zs[3][j] += tc[j]*tc[j];
                    zs[4][j] += pc[j]*tc[j];
                    rp[i][j] = pc[j];  rt[i][j] = tc[j];
                }
            }
        }
    }

    // ---- streaming prefetch of the next add-slice (depth 1) ----
    int za = z0 + RAD;                      // absolute z of next fetch
    int zmax = z0 + ZCHUNK + RAD;           // last useful slice + 1
    if (zmax > DSZ) zmax = DSZ;
    float3 pa3 = {0,0,0}, ta3 = {0,0,0};

#define PF_NEXT() do {                                                        \
    float3 _p = {0,0,0}, _t = {0,0,0};                                        \
    if (ldok && za < zmax) {                                                  \
        _p = *(const float3*)(pred + base + za*SLICE);                        \
        _t = *(const float3*)(tgt  + base + za*SLICE);                        \
    }                                                                         \
    pa3 = _p; ta3 = _t; ++za;                                                 \
} while (0)

    if (stg) PF_NEXT();  // slice for step 0

    int pb = 1;          // parity buffer toggle (first step -> 0)
    float acc = 0.f;

#define NCC_STEP(SLOT) do {                                                   \
    pb ^= 1;                                                                  \
    float* s2w = s2 + pb*S2_BUF;                                              \
    if (stg) {                                                                \
        const float pc[3] = {pa3.x, pa3.y, pa3.z};                            \
        const float tc[3] = {ta3.x, ta3.y, ta3.z};                            \
        PF_NEXT();  /* issue slice s+1; full step to complete */              \
        _Pragma("unroll")                                                     \
        for (int j = 0; j < 3; ++j) {                                         \
            float ps = rp[SLOT][j], qs = rt[SLOT][j];                         \
            float d0 = pc[j] - ps, d1 = tc[j] - qs;                           \
            zs[0][j] += d0;                                                   \
            zs[1][j] += d1;                                                   \
            zs[2][j] += d0*(pc[j] + ps);                                      \
            zs[3][j] += d1*(tc[j] + qs);                                      \
            zs[4][j] += pc[j]*tc[j] - ps*qs;                                  \
            rp[SLOT][j] = pc[j];  rt[SLOT][j] = tc[j];                        \
        }                                                                     \
        _Pragma("unroll")                                                     \
        for (int f = 0; f < 5; ++f) {                                         \
            float v0  = zs[f][0];                                             \
            float v01 = v0 + zs[f][1];                                        \
            float G   = v01 + zs[f][2];        /* 3-col group sum */          \
            float G1 = dpp_shl1(G);                                           \
            float G2 = dpp_shl2(G);                                           \
            float A0 = dpp_shl3(v0);           /* v0(m+3)  */                 \
            float A1 = dpp_shl3(v01);          /* v01(m+3) */                 \
            float S  = G + G1 + G2;            /* halo cols 3m..3m+8 */       \
            float* dst = &s2w[f*S2_FS + row*S2_RS + 3*g];                     \
            if (g < 5) {                                                      \
                dst[0] = S;                    /* out 3m   */                 \
                dst[1] = S - v0  + A0;         /* out 3m+1 */                 \
                dst[2] = S - v01 + A1;         /* out 3m+2 */                 \
            } else if (g == 5) {                                              \
                dst[0] = S;                    /* out 15   */                 \
            }                                                                 \
        }                                                                     \
    }                                                                         \
    __syncthreads();                                                          \
    if (red) {                                                                \
        const int x = tid & 15, yq = ((tid >> 4) & 3)*4;                      \
        float S[5][4];                                                        \
        _Pragma("unroll")                                                     \
        for (int f = 0; f < 5; ++f) {                                         \
            const float* col = &s2w[f*S2_FS + x];                             \
            float r0 = col[(yq+0)*S2_RS], r1 = col[(yq+1)*S2_RS];             \
            float r2 = col[(yq+2)*S2_RS], r3 = col[(yq+3)*S2_RS];             \
            float run = r0+r1+r2+r3 + col[(yq+4)*S2_RS] + col[(yq+5)*S2_RS]   \
                      + col[(yq+6)*S2_RS] + col[(yq+7)*S2_RS];                \
            run += col[(yq+8)*S2_RS];        S[f][0] = run;                   \
            run += col[(yq+9)*S2_RS]  - r0;  S[f][1] = run;                   \
            run += col[(yq+10)*S2_RS] - r1;  S[f][2] = run;                   \
            run += col[(yq+11)*S2_RS] - r2;  S[f][3] = run;                   \
        }                                                                     \
        _Pragma("unroll")                                                     \
        for (int i = 0; i < 4; ++i) {                                         \
            float Sp = S[0][i], St = S[1][i];                                 \
            float cross = S[4][i] - Sp*St*WINV;                               \
            float pv    = S[2][i] - Sp*Sp*WINV;                               \
            float tv    = S[3][i] - St*St*WINV;                               \
            acc += cross*cross / (pv*tv + 1e-8f);                             \
        }                                                                     \
    }                                                                         \
} while (0)

    // steps s=0..3: slots (s+8)%9 = 8,0,1,2
    NCC_STEP(8); NCC_STEP(0); NCC_STEP(1); NCC_STEP(2);
    // steps s=4..39: slot sequence (s+8)%9 is 9-periodic: 3,4,5,6,7,8,0,1,2
    for (int it = 0; it < 4; ++it) {
        NCC_STEP(3); NCC_STEP(4); NCC_STEP(5);
        NCC_STEP(6); NCC_STEP(7); NCC_STEP(8);
        NCC_STEP(0); NCC_STEP(1); NCC_STEP(2);
    }
#undef NCC_STEP
#undef PF_NEXT

    // cc partials live in the reduction wave; fused epilogue on last block
    if (red) {
        float v = acc;
        #pragma unroll
        for (int off = 32; off > 0; off >>= 1) v += __shfl_down(v, off, 64);
        if (tid == 192) {
            atomicAdd(accum, v);
            __threadfence();                       // accum add visible before counter add
            unsigned int old = atomicAdd(counter, 1u);
            if (old == NBLOCKS - 1) {
                // 1600th finisher: all accum adds ordered-before via fences.
                // Read with an atomic RMW (cross-XCD coherent, unlike plain load).
                float a = atomicAdd(accum, 0.0f);
                out[0] = 1.0f - a * NVOX_INV;
            }
        }
    }
}

extern "C" void kernel_launch(void* const* d_in, const int* in_sizes, int n_in,
                              void* d_out, int out_size, void* d_ws, size_t ws_size,
                              hipStream_t stream)
{
    const float* pred = (const float*)d_in[0];
    const float* tgt  = (const float*)d_in[1];
    float* out = (float*)d_out;
    float* accum = (float*)d_ws;
    unsigned int* counter = (unsigned int*)d_ws + 1;

    hipMemsetAsync(d_ws, 0, 2*sizeof(float), stream);   // accum + counter
    dim3 grid(DSZ/TX, DSZ/TY, NBATCH*4);   // 10 x 10 x 16 = 1600 blocks
    ncc_main<<<grid, BLK, 0, stream>>>(pred, tgt, accum, counter, out);
}

// Round 18
// 212.284 us; speedup vs baseline: 1.2749x; 1.2060x over previous
//
#include <hip/hip_runtime.h>

// NCC loss: 1 - mean( cross^2 / (pvar*tvar + 1e-8) ) over 9^3 zero-padded
// box windows, input (4,1,160,160,160) fp32.
//
// R23 == R20 verbatim (the session best: bench 214.1us, FETCH 72MB).
// R22's fused epilogue REGRESSED (kernel 140->158us): the per-block
// device-scope __threadfence forces cache writeback/invalidate that defeats
// the L2/L3 residency the XCD swizzle created. Two-launch structure restored.
//
// Final structure (verdicts from R6-R22, all counter-verified):
//   - R16 core: 3 cols/thread all-lane staging (24 halo cols = 8 groups x 3),
//     54-float register ring, DPP shl1-3 x-prefix, 3 staging waves + 1
//     dedicated reduction wave (BLK 256), ZCHUNK 40, depth-1 prefetch,
//     one __syncthreads per z-step, double-buffered s2 (19.2 KB).
//   - R20 win: bijective XCD swizzle (T1) lid=(bid&7)*200+(bid>>3) gives
//     each XCD two complete 10x10 xy-planes -> halo re-reads are local-L2
//     hits; problem becomes cache-resident (HBM ~7% of peak).
//   - Tested & rejected: barrier micro-plumbing (R8 -23%), step fusion
//     (R10/R17/R19), occupancy-raising (R11/R13/R21), TY=32 (R14/R15),
//     transposed s2 (R18), fused epilogue (R22).

#define DSZ    160
#define NBATCH 4
#define RAD    4
#define TX     16
#define TY     16
#define ZCHUNK 40
#define SLICE  (DSZ*DSZ)
#define VOL    (DSZ*DSZ*DSZ)
#define WINV   (1.0f/729.0f)
#define NVOX_INV (1.0f/16384000.0f)

#define NROW 24        // halo rows per tile
#define BLK  256       // 3 staging waves (tid<192, all active) + 1 reduction wave

#define S2_RS 20                 // row stride: 16 outputs + pad
#define S2_FS (NROW*S2_RS)       // 480 floats per field
#define S2_BUF (5*S2_FS)         // 2400 floats per parity buffer

__device__ __forceinline__ float dpp_shl1(float x) {  // lane i <- lane i+1 (16-lane row, OOB=0)
    return __int_as_float(__builtin_amdgcn_update_dpp(0, __float_as_int(x), 0x101, 0xf, 0xf, true));
}
__device__ __forceinline__ float dpp_shl2(float x) {  // lane i <- lane i+2
    return __int_as_float(__builtin_amdgcn_update_dpp(0, __float_as_int(x), 0x102, 0xf, 0xf, true));
}
__device__ __forceinline__ float dpp_shl3(float x) {  // lane i <- lane i+3
    return __int_as_float(__builtin_amdgcn_update_dpp(0, __float_as_int(x), 0x103, 0xf, 0xf, true));
}

__global__ __launch_bounds__(BLK, 4)
void ncc_main(const float* __restrict__ pred, const float* __restrict__ tgt,
              float* __restrict__ accum)
{
    const int tid = threadIdx.x;
    const int row = tid >> 3;      // 0..23 halo row (staging threads)
    const int g   = tid & 7;       // 0..7 col-triple group; ALL active

    // ---- XCD-aware bijective swizzle (T1): hw bid -> logical tile ----
    // hw dispatch id (x fastest). XCD = bid % 8 (round-robin). Give XCD k a
    // contiguous span of 200 logical tiles = two full 10x10 xy planes.
    const int bid = blockIdx.x + 10*(blockIdx.y + 10*blockIdx.z);
    const int lid = (bid & 7)*200 + (bid >> 3);       // bijective: 1600%8==0
    const int lz  = lid / 100;                        // 0..15: (batch,chunk)
    const int lxy = lid - lz*100;
    const int ly  = lxy / 10;
    const int lx  = lxy - ly*10;

    const int ox  = lx * TX;
    const int oy  = ly * TY;
    const int batch = lz >> 2;
    const int z0  = (lz & 3) * ZCHUNK;

    __shared__ float s2[2*S2_BUF];   // 19.2 KB, double-buffered [f][y][x pad20]

    const bool stg = (tid < 192);
    const bool red = (tid >= 192);               // dedicated reduction wave
    const int  gy  = oy - RAD + row;
    const int  gx0 = ox - RAD + g*3;             // 3 halo cols per thread
    const bool ldok = stg && (gy >= 0) && (gy < DSZ) && (gx0 >= 0) && (gx0 + 2 < DSZ);
    const int  base = batch*VOL + gy*DSZ + gx0;  // only used under ldok

    // register ring of raw slice values (own 3 columns), chunk-local slots
    float rp[9][3], rt[9][3];
    float zs[5][3];
    #pragma unroll
    for (int k = 0; k < 9; ++k)
        #pragma unroll
        for (int j = 0; j < 3; ++j) { rp[k][j] = 0.f; rt[k][j] = 0.f; }
    #pragma unroll
    for (int f = 0; f < 5; ++f)
        #pragma unroll
        for (int j = 0; j < 3; ++j) zs[f][j] = 0.f;

    // ---- warm-up: chunk-local slices 0..7 (z = z0-4 .. z0+3) -> slots 0..7
    if (stg) {
        #pragma unroll
        for (int i = 0; i < 8; ++i) {
            int z = z0 - RAD + i;
            if (z >= 0) {                       // uniform; z < DSZ always here
                float3 p3 = {0,0,0}, t3 = {0,0,0};
                if (ldok) {
                    p3 = *(const float3*)(pred + base + z*SLICE);
                    t3 = *(const float3*)(tgt  + base + z*SLICE);
                }
                const float pc[3] = {p3.x, p3.y, p3.z};
                const float tc[3] = {t3.x, t3.y, t3.z};
                #pragma unroll
                for (int j = 0; j < 3; ++j) {
                    zs[0][j] += pc[j];        zs[1][j] += tc[j];
                    zs[2][j] += pc[j]*pc[j];  zs[3][j] += tc[j]*tc[j];
                    zs[4][j] += pc[j]*tc[j];
                    rp[i][j] = pc[j];  rt[i][j] = tc[j];
                }
            }
        }
    }

    // ---- streaming prefetch of the next add-slice (depth 1) ----
    int za = z0 + RAD;                      // absolute z of next fetch
    int zmax = z0 + ZCHUNK + RAD;           // last useful slice + 1
    if (zmax > DSZ) zmax = DSZ;
    float3 pa3 = {0,0,0}, ta3 = {0,0,0};

#define PF_NEXT() do {                                                        \
    float3 _p = {0,0,0}, _t = {0,0,0};                                        \
    if (ldok && za < zmax) {                                                  \
        _p = *(const float3*)(pred + base + za*SLICE);                        \
        _t = *(const float3*)(tgt  + base + za*SLICE);                        \
    }                                                                         \
    pa3 = _p; ta3 = _t; ++za;                                                 \
} while (0)

    if (stg) PF_NEXT();  // slice for step 0

    int pb = 1;          // parity buffer toggle (first step -> 0)
    float acc = 0.f;

#define NCC_STEP(SLOT) do {                                                   \
    pb ^= 1;                                                                  \
    float* s2w = s2 + pb*S2_BUF;                                              \
    if (stg) {                                                                \
        const float pc[3] = {pa3.x, pa3.y, pa3.z};                            \
        const float tc[3] = {ta3.x, ta3.y, ta3.z};                            \
        PF_NEXT();  /* issue slice s+1; full step to complete */              \
        _Pragma("unroll")                                                     \
        for (int j = 0; j < 3; ++j) {                                         \
            float ps = rp[SLOT][j], qs = rt[SLOT][j];                         \
            float d0 = pc[j] - ps, d1 = tc[j] - qs;                           \
            zs[0][j] += d0;                                                   \
            zs[1][j] += d1;                                                   \
            zs[2][j] += d0*(pc[j] + ps);                                      \
            zs[3][j] += d1*(tc[j] + qs);                                      \
            zs[4][j] += pc[j]*tc[j] - ps*qs;                                  \
            rp[SLOT][j] = pc[j];  rt[SLOT][j] = tc[j];                        \
        }                                                                     \
        _Pragma("unroll")                                                     \
        for (int f = 0; f < 5; ++f) {                                         \
            float v0  = zs[f][0];                                             \
            float v01 = v0 + zs[f][1];                                        \
            float G   = v01 + zs[f][2];        /* 3-col group sum */          \
            float G1 = dpp_shl1(G);                                           \
            float G2 = dpp_shl2(G);                                           \
            float A0 = dpp_shl3(v0);           /* v0(m+3)  */                 \
            float A1 = dpp_shl3(v01);          /* v01(m+3) */                 \
            float S  = G + G1 + G2;            /* halo cols 3m..3m+8 */       \
            float* dst = &s2w[f*S2_FS + row*S2_RS + 3*g];                     \
            if (g < 5) {                                                      \
                dst[0] = S;                    /* out 3m   */                 \
                dst[1] = S - v0  + A0;         /* out 3m+1 */                 \
                dst[2] = S - v01 + A1;         /* out 3m+2 */                 \
            } else if (g == 5) {                                              \
                dst[0] = S;                    /* out 15   */                 \
            }                                                                 \
        }                                                                     \
    }                                                                         \
    __syncthreads();                                                          \
    if (red) {                                                                \
        const int x = tid & 15, yq = ((tid >> 4) & 3)*4;                      \
        float S[5][4];                                                        \
        _Pragma("unroll")                                                     \
        for (int f = 0; f < 5; ++f) {                                         \
            const float* col = &s2w[f*S2_FS + x];                             \
            float r0 = col[(yq+0)*S2_RS], r1 = col[(yq+1)*S2_RS];             \
            float r2 = col[(yq+2)*S2_RS], r3 = col[(yq+3)*S2_RS];             \
            float run = r0+r1+r2+r3 + col[(yq+4)*S2_RS] + col[(yq+5)*S2_RS]   \
                      + col[(yq+6)*S2_RS] + col[(yq+7)*S2_RS];                \
            run += col[(yq+8)*S2_RS];        S[f][0] = run;                   \
            run += col[(yq+9)*S2_RS]  - r0;  S[f][1] = run;                   \
            run += col[(yq+10)*S2_RS] - r1;  S[f][2] = run;                   \
            run += col[(yq+11)*S2_RS] - r2;  S[f][3] = run;                   \
        }                                                                     \
        _Pragma("unroll")                                                     \
        for (int i = 0; i < 4; ++i) {                                         \
            float Sp = S[0][i], St = S[1][i];                                 \
            float cross = S[4][i] - Sp*St*WINV;                               \
            float pv    = S[2][i] - Sp*Sp*WINV;                               \
            float tv    = S[3][i] - St*St*WINV;                               \
            acc += cross*cross / (pv*tv + 1e-8f);                             \
        }                                                                     \
    }                                                                         \
} while (0)

    // steps s=0..3: slots (s+8)%9 = 8,0,1,2
    NCC_STEP(8); NCC_STEP(0); NCC_STEP(1); NCC_STEP(2);
    // steps s=4..39: slot sequence (s+8)%9 is 9-periodic: 3,4,5,6,7,8,0,1,2
    for (int it = 0; it < 4; ++it) {
        NCC_STEP(3); NCC_STEP(4); NCC_STEP(5);
        NCC_STEP(6); NCC_STEP(7); NCC_STEP(8);
        NCC_STEP(0); NCC_STEP(1); NCC_STEP(2);
    }
#undef NCC_STEP
#undef PF_NEXT

    // all cc partials live in the reduction wave (tid 192..255)
    if (red) {
        float v = acc;
        #pragma unroll
        for (int off = 32; off > 0; off >>= 1) v += __shfl_down(v, off, 64);
        if (tid == 192) atomicAdd(accum, v);
    }
}

__global__ void ncc_final(const float* __restrict__ accum, float* __restrict__ out)
{
    out[0] = 1.0f - accum[0] * NVOX_INV;
}

extern "C" void kernel_launch(void* const* d_in, const int* in_sizes, int n_in,
                              void* d_out, int out_size, void* d_ws, size_t ws_size,
                              hipStream_t stream)
{
    const float* pred = (const float*)d_in[0];
    const float* tgt  = (const float*)d_in[1];
    float* out = (float*)d_out;
    float* ws  = (float*)d_ws;

    hipMemsetAsync(ws, 0, sizeof(float), stream);
    dim3 grid(DSZ/TX, DSZ/TY, NBATCH*4);   // 10 x 10 x 16 = 1600 blocks
    ncc_main<<<grid, BLK, 0, stream>>>(pred, tgt, ws);
    ncc_final<<<1, 1, 0, stream>>>(ws, out);
}